// Round 1
// baseline (1735.840 us; speedup 1.0000x reference)
//
#include <hip/hip_runtime.h>
#include <math.h>

#define B 256
#define F 512
#define C 100000
#define S_SCALE 64.0f
#define M_MARGIN 0.4f
#define K_VP 0.7f

#define TILE_C 64
#define KC 32
#define NTILES ((C + TILE_C - 1) / TILE_C)   // 1563

// ---------- emb = l2norm(input, 1e-5) ----------
__global__ void emb_kernel(const float* __restrict__ input, float* __restrict__ emb) {
    int i = blockIdx.x;
    int t = threadIdx.x;
    const float* x = input + (size_t)i * F;
    float x0 = x[t], x1 = x[t + 256];
    float p = x0 * x0 + x1 * x1;
    __shared__ float red[4];
    for (int off = 32; off > 0; off >>= 1) p += __shfl_down(p, off, 64);
    if ((t & 63) == 0) red[t >> 6] = p;
    __syncthreads();
    float tot = red[0] + red[1] + red[2] + red[3];
    float inv = 1.0f / fmaxf(sqrtf(tot), 1e-5f);
    emb[(size_t)i * F + t]       = x0 * inv;
    emb[(size_t)i * F + t + 256] = x1 * inv;
}

// ---------- map[c] = -1 ; negacc = 0 ----------
__global__ void init_kernel(int* __restrict__ map, float* __restrict__ negacc) {
    int idx = blockIdx.x * 256 + threadIdx.x;
    if (idx < C) map[idx] = -1;
    if (idx < 2 * B) negacc[idx] = 0.0f;
}

// ---------- last-occurrence-wins scatter map (numpy queue[label]=rows semantics) ----------
__global__ void scatter_kernel(const int* __restrict__ label, int* __restrict__ map) {
    int t = threadIdx.x;
    atomicMax(&map[label[t]], t);
}

// ---------- new_rows[i] = l2norm(softsign(drift)*q + (1-softsign)*emb, 1e-12) ----------
__global__ void newrows_kernel(const float* __restrict__ queue, const float* __restrict__ emb,
                               const int* __restrict__ label, float* __restrict__ newrows) {
    int i = blockIdx.x;
    int t = threadIdx.x;
    int l = label[i];
    const float* q = queue + (size_t)l * F;
    const float* e = emb + (size_t)i * F;
    float q0 = q[t], q1 = q[t + 256];
    float e0 = e[t], e1 = e[t + 256];
    float p = q0 * e0 + q1 * e1;
    __shared__ float red[4];
    for (int off = 32; off > 0; off >>= 1) p += __shfl_down(p, off, 64);
    if ((t & 63) == 0) red[t >> 6] = p;
    __syncthreads();
    float drift = red[0] + red[1] + red[2] + red[3];
    float f = drift / (1.0f + fabsf(drift));   // softsign
    float v0 = f * q0 + (1.0f - f) * e0;
    float v1 = f * q1 + (1.0f - f) * e1;
    float p2 = v0 * v0 + v1 * v1;
    __syncthreads();
    for (int off = 32; off > 0; off >>= 1) p2 += __shfl_down(p2, off, 64);
    if ((t & 63) == 0) red[t >> 6] = p2;
    __syncthreads();
    float tot = red[0] + red[1] + red[2] + red[3];
    float inv = 1.0f / fmaxf(sqrtf(tot), 1e-12f);
    newrows[(size_t)i * F + t]       = v0 * inv;
    newrows[(size_t)i * F + t + 256] = v1 * inv;
}

// ---------- fused GEMM + on-the-fly column norm + exp-sum epilogue ----------
// src 0: weight (eps 1e-5), src 1: queue_upd (eps 1e-12, map override to newrows)
__global__ __launch_bounds__(256) void gemm_epl_kernel(
        const float* __restrict__ emb,
        const float* __restrict__ weight,
        const float* __restrict__ queue,
        const float* __restrict__ newrows,
        const int* __restrict__ map,
        const int* __restrict__ label,
        float* __restrict__ negacc,
        float* __restrict__ posvals) {
    int bx = blockIdx.x;
    int src = bx / NTILES;
    int tile = bx % NTILES;
    int c0 = tile * TILE_C;
    int tid = threadIdx.x;
    int rg = tid >> 3;   // 0..31, 8 rows each
    int cg = tid & 7;    // 0..7,  8 cols each

    __shared__ float emb_s[B][KC + 1];        // stride 33: 2-way bank alias only (free)
    __shared__ float col_s[KC][TILE_C];       // [k][col]
    __shared__ const float* colbase_s[TILE_C];
    __shared__ float colinv_s[TILE_C];
    __shared__ int label_s[B];

    if (tid < B) label_s[tid] = label[tid];
    if (tid < TILE_C) {
        int c = c0 + tid;
        const float* p = nullptr;
        if (c < C) {
            if (src == 0) p = weight + (size_t)c * F;
            else {
                int mi = map[c];
                p = (mi >= 0) ? (newrows + (size_t)mi * F) : (queue + (size_t)c * F);
            }
        }
        colbase_s[tid] = p;
    }

    float acc[8][8];
#pragma unroll
    for (int r = 0; r < 8; ++r)
#pragma unroll
        for (int j = 0; j < 8; ++j) acc[r][j] = 0.0f;
    float csum = 0.0f;

    for (int kc = 0; kc < F / KC; ++kc) {
        int k0 = kc * KC;
        __syncthreads();
        // stage emb chunk: 256 rows x 32 k = 2048 float4, 8 per thread
#pragma unroll
        for (int m = 0; m < 8; ++m) {
            int f4 = tid + m * 256;
            int row = f4 >> 3;
            int kq = f4 & 7;
            const float4 v = *(const float4*)(emb + (size_t)row * F + k0 + kq * 4);
            emb_s[row][kq * 4 + 0] = v.x;
            emb_s[row][kq * 4 + 1] = v.y;
            emb_s[row][kq * 4 + 2] = v.z;
            emb_s[row][kq * 4 + 3] = v.w;
        }
        // stage col chunk: 64 cols x 32 k = 512 float4, 2 per thread
#pragma unroll
        for (int m = 0; m < 2; ++m) {
            int f4 = tid + m * 256;
            int cl = f4 >> 3;
            int kq = f4 & 7;
            const float* p = colbase_s[cl];
            float4 v = make_float4(0.0f, 0.0f, 0.0f, 0.0f);
            if (p) v = *(const float4*)(p + k0 + kq * 4);
            col_s[kq * 4 + 0][cl] = v.x;
            col_s[kq * 4 + 1][cl] = v.y;
            col_s[kq * 4 + 2][cl] = v.z;
            col_s[kq * 4 + 3][cl] = v.w;
        }
        __syncthreads();
        // on-the-fly column sumsq (threads 0..63, one column each)
        if (tid < TILE_C) {
#pragma unroll
            for (int k = 0; k < KC; ++k) { float v = col_s[k][tid]; csum += v * v; }
        }
        // 8x8 register-tile FMA
#pragma unroll
        for (int k = 0; k < KC; ++k) {
            float a[8], b[8];
#pragma unroll
            for (int r = 0; r < 8; ++r) a[r] = emb_s[rg * 8 + r][k];
#pragma unroll
            for (int j = 0; j < 8; ++j) b[j] = col_s[k][cg * 8 + j];
#pragma unroll
            for (int r = 0; r < 8; ++r)
#pragma unroll
                for (int j = 0; j < 8; ++j) acc[r][j] += a[r] * b[j];
        }
    }
    __syncthreads();
    if (tid < TILE_C) {
        float eps = (src == 0) ? 1e-5f : 1e-12f;
        colinv_s[tid] = 1.0f / fmaxf(sqrtf(csum), eps);
    }
    __syncthreads();

    // epilogue: cos = dot * colinv; label column -> posvals; others -> sum exp(64*cos)
    float negpart[8];
#pragma unroll
    for (int r = 0; r < 8; ++r) negpart[r] = 0.0f;
#pragma unroll
    for (int r = 0; r < 8; ++r) {
        int row = rg * 8 + r;
        int lab = label_s[row];
#pragma unroll
        for (int j = 0; j < 8; ++j) {
            int c = c0 + cg * 8 + j;
            if (c < C) {
                float cosv = acc[r][j] * colinv_s[cg * 8 + j];
                if (c == lab) {
                    posvals[src * B + row] = cosv;   // unique writer per (src,row)
                } else {
                    negpart[r] += __expf(S_SCALE * cosv);
                }
            }
        }
    }
    // reduce across the 8 col-groups (lanes differing in low 3 bits), then 1 atomic/row
#pragma unroll
    for (int r = 0; r < 8; ++r) {
        float v = negpart[r];
        v += __shfl_xor(v, 1, 64);
        v += __shfl_xor(v, 2, 64);
        v += __shfl_xor(v, 4, 64);
        if (cg == 0) atomicAdd(&negacc[src * B + rg * 8 + r], v);
    }
}

// ---------- final EPL loss ----------
__global__ void loss_kernel(const float* __restrict__ negacc, const float* __restrict__ posvals,
                            float* __restrict__ out) {
    int t = threadIdx.x;  // 256
    // row t (cosine half): pos logit = 64*(cos - 0.4)
    float l1 = log1pf(negacc[t] * __expf(-S_SCALE * (posvals[t] - M_MARGIN)));
    // row B+t (vp half): diag -> (1-0.7)*diag
    float l2 = log1pf(negacc[B + t] * __expf(-S_SCALE * (1.0f - K_VP) * posvals[B + t]));
    float p = l1 + l2;
    __shared__ float red[4];
    for (int off = 32; off > 0; off >>= 1) p += __shfl_down(p, off, 64);
    if ((t & 63) == 0) red[t >> 6] = p;
    __syncthreads();
    if (t == 0) out[0] = (red[0] + red[1] + red[2] + red[3]) / (2.0f * B);
}

extern "C" void kernel_launch(void* const* d_in, const int* in_sizes, int n_in,
                              void* d_out, int out_size, void* d_ws, size_t ws_size,
                              hipStream_t stream) {
    const float* input  = (const float*)d_in[0];
    const float* weight = (const float*)d_in[1];
    const float* queue  = (const float*)d_in[2];
    const int*   label  = (const int*)d_in[3];
    // d_in[4] = epoch (unused: epoch+1 >= 4 branch is always taken in the reference)
    float* out = (float*)d_out;

    char* ws = (char*)d_ws;
    float* emb     = (float*)(ws);                          // 256*512 f32 = 512 KB
    float* newrows = (float*)(ws + (512 << 10));            // 256*512 f32 = 512 KB
    float* negacc  = (float*)(ws + (1024 << 10));           // 512 f32
    float* posvals = (float*)(ws + (1024 << 10) + 2048);    // 512 f32
    int*   map     = (int*)  (ws + (1024 << 10) + 4096);    // 100000 int

    emb_kernel<<<B, 256, 0, stream>>>(input, emb);
    init_kernel<<<(C + 255) / 256, 256, 0, stream>>>(map, negacc);
    scatter_kernel<<<1, B, 0, stream>>>(label, map);
    newrows_kernel<<<B, 256, 0, stream>>>(queue, emb, label, newrows);
    gemm_epl_kernel<<<2 * NTILES, 256, 0, stream>>>(emb, weight, queue, newrows, map,
                                                    label, negacc, posvals);
    loss_kernel<<<1, 256, 0, stream>>>(negacc, posvals, out);
}

// Round 2
// 714.260 us; speedup vs baseline: 2.4303x; 2.4303x over previous
//
#include <hip/hip_runtime.h>
#include <math.h>

#define B 256
#define F 512
#define C 100000
#define S_SCALE 64.0f
#define M_MARGIN 0.4f
#define K_VP 0.7f

#define BN 64
#define BK 64
#define NTILES ((C + BN - 1) / BN)   // 1563
#define LDK (BK + 8)                  // +8 bf16 pad -> 2-way bank alias only (free)

typedef __bf16 bf16x8 __attribute__((ext_vector_type(8)));
typedef __bf16 bf16x4 __attribute__((ext_vector_type(4)));
typedef float  floatx4 __attribute__((ext_vector_type(4)));

// ---------- emb = l2norm(input, 1e-5), fp32 + bf16 copies ----------
__global__ void emb_kernel(const float* __restrict__ input, float* __restrict__ emb,
                           __bf16* __restrict__ embb) {
    int i = blockIdx.x;
    int t = threadIdx.x;
    const float* x = input + (size_t)i * F;
    float x0 = x[t], x1 = x[t + 256];
    float p = x0 * x0 + x1 * x1;
    __shared__ float red[4];
    for (int off = 32; off > 0; off >>= 1) p += __shfl_down(p, off, 64);
    if ((t & 63) == 0) red[t >> 6] = p;
    __syncthreads();
    float tot = red[0] + red[1] + red[2] + red[3];
    float inv = 1.0f / fmaxf(sqrtf(tot), 1e-5f);
    float e0 = x0 * inv, e1 = x1 * inv;
    emb[(size_t)i * F + t]       = e0;
    emb[(size_t)i * F + t + 256] = e1;
    embb[(size_t)i * F + t]       = (__bf16)e0;
    embb[(size_t)i * F + t + 256] = (__bf16)e1;
}

// ---------- map[c] = -1 ; negacc = 0 ----------
__global__ void init_kernel(int* __restrict__ map, float* __restrict__ negacc) {
    int idx = blockIdx.x * 256 + threadIdx.x;
    if (idx < C) map[idx] = -1;
    if (idx < 2 * B) negacc[idx] = 0.0f;
}

// ---------- last-occurrence-wins scatter (numpy queue[label]=rows semantics) ----------
__global__ void scatter_kernel(const int* __restrict__ label, int* __restrict__ map) {
    atomicMax(&map[label[threadIdx.x]], (int)threadIdx.x);
}

// ---------- new_rows[i] = l2norm(softsign(drift)*q + (1-softsign)*emb, 1e-12) (exact fp32) ----------
__global__ void newrows_kernel(const float* __restrict__ queue, const float* __restrict__ emb,
                               const int* __restrict__ label, float* __restrict__ newrows) {
    int i = blockIdx.x;
    int t = threadIdx.x;
    int l = label[i];
    const float* q = queue + (size_t)l * F;
    const float* e = emb + (size_t)i * F;
    float q0 = q[t], q1 = q[t + 256];
    float e0 = e[t], e1 = e[t + 256];
    float p = q0 * e0 + q1 * e1;
    __shared__ float red[4];
    for (int off = 32; off > 0; off >>= 1) p += __shfl_down(p, off, 64);
    if ((t & 63) == 0) red[t >> 6] = p;
    __syncthreads();
    float drift = red[0] + red[1] + red[2] + red[3];
    float f = drift / (1.0f + fabsf(drift));   // softsign
    float v0 = f * q0 + (1.0f - f) * e0;
    float v1 = f * q1 + (1.0f - f) * e1;
    float p2 = v0 * v0 + v1 * v1;
    __syncthreads();
    for (int off = 32; off > 0; off >>= 1) p2 += __shfl_down(p2, off, 64);
    if ((t & 63) == 0) red[t >> 6] = p2;
    __syncthreads();
    float tot = red[0] + red[1] + red[2] + red[3];
    float inv = 1.0f / fmaxf(sqrtf(tot), 1e-12f);
    newrows[(size_t)i * F + t]       = v0 * inv;
    newrows[(size_t)i * F + t + 256] = v1 * inv;
}

// ---------- bf16 MFMA GEMM (256 x 64 tile) + fly column-norm + EPL exp epilogue ----------
// src 0: weight (eps 1e-5); src 1: queue_upd (eps 1e-12, map -> newrows override)
__global__ __launch_bounds__(256) void gemm_epl_kernel(
        const __bf16* __restrict__ embb,
        const float* __restrict__ weight,
        const float* __restrict__ queue,
        const float* __restrict__ newrows,
        const int* __restrict__ map,
        const int* __restrict__ label,
        float* __restrict__ negacc,
        float* __restrict__ posvals) {
    int bx = blockIdx.x;
    int src = bx / NTILES;
    int tile = bx - src * NTILES;
    int c0 = tile * BN;
    int tid = threadIdx.x;
    int w = tid >> 6;
    int lane = tid & 63;
    int ln = lane & 15;
    int q = lane >> 4;

    __shared__ __align__(16) __bf16 a_s[B][LDK];     // 36864 B
    __shared__ __align__(16) __bf16 b_s[BN][LDK];    //  9216 B
    __shared__ float colinv_s[BN];
    __shared__ float colpart_s[BN][17];
    __shared__ int label_s[B];
    __shared__ const float* colbase_s[BN];

    if (tid < B) label_s[tid] = label[tid];
    if (tid < BN) {
        int c = c0 + tid;
        const float* p = nullptr;
        if (c < C) {
            if (src == 0) p = weight + (size_t)c * F;
            else {
                int mi = map[c];
                p = (mi >= 0) ? (newrows + (size_t)mi * F) : (queue + (size_t)c * F);
            }
        }
        colbase_s[tid] = p;
    }

    floatx4 acc[4][4];
#pragma unroll
    for (int rt = 0; rt < 4; ++rt)
#pragma unroll
        for (int ct = 0; ct < 4; ++ct) acc[rt][ct] = (floatx4){0.f, 0.f, 0.f, 0.f};
    float ssq[4] = {0.f, 0.f, 0.f, 0.f};

    for (int kc = 0; kc < F / BK; ++kc) {
        int k0 = kc * BK;
        __syncthreads();
        // stage emb chunk (bf16, from L2): 256 rows x 64 k, 8 x 16B per thread
#pragma unroll
        for (int i = 0; i < 8; ++i) {
            int row = (tid >> 3) + 32 * i;
            bf16x8 v = *(const bf16x8*)(embb + (size_t)row * F + k0 + (tid & 7) * 8);
            *(bf16x8*)&a_s[row][(tid & 7) * 8] = v;
        }
        // stage col chunk (fp32 stream -> fp32 sumsq -> bf16): 4 x float4 per thread
#pragma unroll
        for (int i = 0; i < 4; ++i) {
            int cl = (tid >> 4) + 16 * i;
            const float* p = colbase_s[cl];
            float4 v = make_float4(0.f, 0.f, 0.f, 0.f);
            if (p) v = *(const float4*)(p + k0 + (tid & 15) * 4);
            ssq[i] += v.x * v.x + v.y * v.y + v.z * v.z + v.w * v.w;
            bf16x4 bv;
            bv[0] = (__bf16)v.x; bv[1] = (__bf16)v.y; bv[2] = (__bf16)v.z; bv[3] = (__bf16)v.w;
            *(bf16x4*)&b_s[cl][(tid & 15) * 4] = bv;
        }
        __syncthreads();
#pragma unroll
        for (int ks = 0; ks < 2; ++ks) {
            int kk = ks * 32 + q * 8;
            bf16x8 af[4], bfr[4];
#pragma unroll
            for (int rt = 0; rt < 4; ++rt) af[rt] = *(const bf16x8*)&a_s[w * 64 + rt * 16 + ln][kk];
#pragma unroll
            for (int ct = 0; ct < 4; ++ct) bfr[ct] = *(const bf16x8*)&b_s[ct * 16 + ln][kk];
#pragma unroll
            for (int rt = 0; rt < 4; ++rt)
#pragma unroll
                for (int ct = 0; ct < 4; ++ct)
                    acc[rt][ct] = __builtin_amdgcn_mfma_f32_16x16x32_bf16(af[rt], bfr[ct], acc[rt][ct], 0, 0, 0);
        }
    }

    // reduce fp32 column sumsq (16 partial threads per column)
#pragma unroll
    for (int i = 0; i < 4; ++i) colpart_s[(tid >> 4) + 16 * i][tid & 15] = ssq[i];
    __syncthreads();
    if (tid < BN) {
        float s = 0.f;
#pragma unroll
        for (int j = 0; j < 16; ++j) s += colpart_s[tid][j];
        float eps = (src == 0) ? 1e-5f : 1e-12f;
        colinv_s[tid] = 1.0f / fmaxf(sqrtf(s), eps);
    }
    __syncthreads();

    // epilogue: cos = dot * colinv; label col -> posvals; others -> sum exp(64*cos)
#pragma unroll
    for (int rt = 0; rt < 4; ++rt) {
#pragma unroll
        for (int r = 0; r < 4; ++r) {
            int row = w * 64 + rt * 16 + q * 4 + r;
            int lab = label_s[row];
            float sum = 0.f;
#pragma unroll
            for (int ct = 0; ct < 4; ++ct) {
                int c = c0 + ct * 16 + ln;
                if (c < C) {
                    float cosv = acc[rt][ct][r] * colinv_s[ct * 16 + ln];
                    if (c == lab) posvals[src * B + row] = cosv;  // unique writer per (src,row)
                    else sum += __expf(S_SCALE * cosv);
                }
            }
            sum += __shfl_xor(sum, 1, 64);
            sum += __shfl_xor(sum, 2, 64);
            sum += __shfl_xor(sum, 4, 64);
            sum += __shfl_xor(sum, 8, 64);
            if (ln == 0) atomicAdd(&negacc[src * B + row], sum);
        }
    }
}

// ---------- final EPL loss ----------
__global__ void loss_kernel(const float* __restrict__ negacc, const float* __restrict__ posvals,
                            float* __restrict__ out) {
    int t = threadIdx.x;  // 256
    float l1 = log1pf(negacc[t] * __expf(-S_SCALE * (posvals[t] - M_MARGIN)));
    float l2 = log1pf(negacc[B + t] * __expf(-S_SCALE * (1.0f - K_VP) * posvals[B + t]));
    float p = l1 + l2;
    __shared__ float red[4];
    for (int off = 32; off > 0; off >>= 1) p += __shfl_down(p, off, 64);
    if ((t & 63) == 0) red[t >> 6] = p;
    __syncthreads();
    if (t == 0) out[0] = (red[0] + red[1] + red[2] + red[3]) / (2.0f * B);
}

extern "C" void kernel_launch(void* const* d_in, const int* in_sizes, int n_in,
                              void* d_out, int out_size, void* d_ws, size_t ws_size,
                              hipStream_t stream) {
    const float* input  = (const float*)d_in[0];
    const float* weight = (const float*)d_in[1];
    const float* queue  = (const float*)d_in[2];
    const int*   label  = (const int*)d_in[3];
    float* out = (float*)d_out;

    char* ws = (char*)d_ws;
    float*  emb     = (float*)(ws);                          // 512 KB
    float*  newrows = (float*)(ws + (512 << 10));            // 512 KB
    __bf16* embb    = (__bf16*)(ws + (1024 << 10));          // 256 KB
    float*  negacc  = (float*)(ws + (1280 << 10));           // 2 KB
    float*  posvals = (float*)(ws + (1280 << 10) + 2048);    // 2 KB
    int*    map     = (int*)  (ws + (1280 << 10) + 4096);    // 400 KB

    emb_kernel<<<B, 256, 0, stream>>>(input, emb, embb);
    init_kernel<<<(C + 255) / 256, 256, 0, stream>>>(map, negacc);
    scatter_kernel<<<1, B, 0, stream>>>(label, map);
    newrows_kernel<<<B, 256, 0, stream>>>(queue, emb, label, newrows);
    gemm_epl_kernel<<<2 * NTILES, 256, 0, stream>>>(embb, weight, queue, newrows, map,
                                                    label, negacc, posvals);
    loss_kernel<<<1, 256, 0, stream>>>(negacc, posvals, out);
}

// Round 3
// 689.767 us; speedup vs baseline: 2.5166x; 1.0355x over previous
//
#include <hip/hip_runtime.h>
#include <math.h>

#define B 256
#define F 512
#define C 100000
#define S_SCALE 64.0f
#define M_MARGIN 0.4f
#define K_VP 0.7f

#define BN 64
#define NTILES ((C + BN - 1) / BN)   // 1563
#define LDB 520                       // bf16 LDS stride per column (520*2=1040 B)

typedef __bf16 bf16x8 __attribute__((ext_vector_type(8)));
typedef __bf16 bf16x4 __attribute__((ext_vector_type(4)));
typedef float  floatx4 __attribute__((ext_vector_type(4)));

// ---------- fused: emb = l2norm(input) -> swizzled bf16 A + newrows (exact fp32) ----------
// embb_sw layout: A-frag for (rowtile R, kstep ks) at 1KB block ((R*16+ks)*64 + lane)*16B,
// lane = (row&15) + 16*q, element j: k = ks*32 + q*8 + j.
__global__ void embnew_kernel(const float* __restrict__ input, const float* __restrict__ queue,
                              const int* __restrict__ label,
                              __bf16* __restrict__ embb_sw, float* __restrict__ newrows) {
    int i = blockIdx.x;
    int t = threadIdx.x;
    const float* x = input + (size_t)i * F;
    float x0 = x[t], x1 = x[t + 256];
    float p = x0 * x0 + x1 * x1;
    __shared__ float red[4];
    for (int off = 32; off > 0; off >>= 1) p += __shfl_down(p, off, 64);
    if ((t & 63) == 0) red[t >> 6] = p;
    __syncthreads();
    float tot = red[0] + red[1] + red[2] + red[3];
    float inv = 1.0f / fmaxf(sqrtf(tot), 1e-5f);
    float e0 = x0 * inv, e1 = x1 * inv;
    // swizzled bf16 writes for k=t and k=t+256
    {
        int R = i >> 4, ln = i & 15;
        int k = t;
        embb_sw[(size_t)(((R * 16 + (k >> 5)) * 64 + ln + 16 * ((k & 31) >> 3)) * 8 + (k & 7))] = (__bf16)e0;
        k = t + 256;
        embb_sw[(size_t)(((R * 16 + (k >> 5)) * 64 + ln + 16 * ((k & 31) >> 3)) * 8 + (k & 7))] = (__bf16)e1;
    }
    // newrows (needs only this row's emb)
    int l = label[i];
    const float* qr = queue + (size_t)l * F;
    float q0 = qr[t], q1 = qr[t + 256];
    float pd = q0 * e0 + q1 * e1;
    __syncthreads();
    for (int off = 32; off > 0; off >>= 1) pd += __shfl_down(pd, off, 64);
    if ((t & 63) == 0) red[t >> 6] = pd;
    __syncthreads();
    float drift = red[0] + red[1] + red[2] + red[3];
    float f = drift / (1.0f + fabsf(drift));   // softsign
    float v0 = f * q0 + (1.0f - f) * e0;
    float v1 = f * q1 + (1.0f - f) * e1;
    float p2 = v0 * v0 + v1 * v1;
    __syncthreads();
    for (int off = 32; off > 0; off >>= 1) p2 += __shfl_down(p2, off, 64);
    if ((t & 63) == 0) red[t >> 6] = p2;
    __syncthreads();
    float tot2 = red[0] + red[1] + red[2] + red[3];
    float inv2 = 1.0f / fmaxf(sqrtf(tot2), 1e-12f);
    newrows[(size_t)i * F + t]       = v0 * inv2;
    newrows[(size_t)i * F + t + 256] = v1 * inv2;
}

// ---------- map[c] = -1 ; negacc = 0 ----------
__global__ void init_kernel(int* __restrict__ map, float* __restrict__ negacc) {
    int idx = blockIdx.x * 256 + threadIdx.x;
    if (idx < C) map[idx] = -1;
    if (idx < 2 * B) negacc[idx] = 0.0f;
}

// ---------- last-occurrence-wins scatter (numpy queue[label]=rows semantics) ----------
__global__ void scatter_kernel(const int* __restrict__ label, int* __restrict__ map) {
    atomicMax(&map[label[threadIdx.x]], (int)threadIdx.x);
}

// ---------- bf16 MFMA GEMM: whole 64x512 B-tile staged at once; A-frags from L2 ----------
__global__ __launch_bounds__(256, 2) void gemm_epl_kernel(
        const __bf16* __restrict__ embb_sw,
        const float* __restrict__ weight,
        const float* __restrict__ queue,
        const float* __restrict__ newrows,
        const int* __restrict__ map,
        const int* __restrict__ label,
        float* __restrict__ negacc,
        float* __restrict__ posvals) {
    int bx = blockIdx.x;
    int src = bx / NTILES;
    int tile = bx - src * NTILES;
    int c0 = tile * BN;
    int tid = threadIdx.x;
    int w = tid >> 6;
    int l = tid & 63;
    int ln = l & 15;
    int q = l >> 4;

    __shared__ __align__(16) __bf16 b_s[BN][LDB];   // 66560 B
    __shared__ float colinv_s[BN];
    __shared__ float colpart_s[BN][4];
    __shared__ int label_s[B];
    __shared__ const float* colbase_s[BN];

    if (tid < B) label_s[tid] = label[tid];
    if (tid < BN) {
        int c = c0 + tid;
        const float* p = nullptr;
        if (c < C) {
            if (src == 0) p = weight + (size_t)c * F;
            else {
                int mi = map[c];
                p = (mi >= 0) ? (newrows + (size_t)mi * F) : (queue + (size_t)c * F);
            }
        }
        colbase_s[tid] = p;
    }
    __syncthreads();

    // ---- stage whole tile: 64 cols x 512 k fp32 -> bf16 LDS. 2 passes x 16 float4/thread.
    // pass p: col = (tid>>3) + 32p; float4 index (tid&7) + 8j -> 8 lanes x 16B = 128B/col segment.
#pragma unroll
    for (int p = 0; p < 2; ++p) {
        int c = (tid >> 3) + 32 * p;
        const float* bp = colbase_s[c];
        float4 v[16];
#pragma unroll
        for (int j = 0; j < 16; ++j) {
            v[j] = bp ? *(const float4*)(bp + ((size_t)((tid & 7) + 8 * j)) * 4)
                      : make_float4(0.f, 0.f, 0.f, 0.f);
        }
#pragma unroll
        for (int j = 0; j < 16; ++j) {
            bf16x4 bv;
            bv[0] = (__bf16)v[j].x; bv[1] = (__bf16)v[j].y;
            bv[2] = (__bf16)v[j].z; bv[3] = (__bf16)v[j].w;
            *(bf16x4*)&b_s[c][((tid & 7) + 8 * j) * 4] = bv;
        }
    }
    __syncthreads();

    // ---- column sumsq from bf16 LDS (rel err ~1e-4, negligible): 4 threads/col x 128 elems
    {
        int c = tid & 63, quarter = tid >> 6;
        float ss = 0.f;
#pragma unroll
        for (int j = 0; j < 16; ++j) {
            bf16x8 x = *(const bf16x8*)&b_s[c][quarter * 128 + j * 8];
#pragma unroll
            for (int e = 0; e < 8; ++e) { float f = (float)x[e]; ss += f * f; }
        }
        colpart_s[c][quarter] = ss;
    }

    // ---- MFMA main loop: wave w -> rows 64w..64w+63; A-frags stream from L2 (1KB coalesced)
    floatx4 acc[4][4];
#pragma unroll
    for (int rt = 0; rt < 4; ++rt)
#pragma unroll
        for (int ct = 0; ct < 4; ++ct) acc[rt][ct] = (floatx4){0.f, 0.f, 0.f, 0.f};

#pragma unroll
    for (int ks = 0; ks < 16; ++ks) {
        bf16x8 af[4], bfr[4];
#pragma unroll
        for (int rt = 0; rt < 4; ++rt)
            af[rt] = *(const bf16x8*)(embb_sw + ((size_t)(((w * 4 + rt) * 16 + ks) * 64 + l) << 3));
#pragma unroll
        for (int ct = 0; ct < 4; ++ct)
            bfr[ct] = *(const bf16x8*)&b_s[ct * 16 + ln][ks * 32 + q * 8];
#pragma unroll
        for (int rt = 0; rt < 4; ++rt)
#pragma unroll
            for (int ct = 0; ct < 4; ++ct)
                acc[rt][ct] = __builtin_amdgcn_mfma_f32_16x16x32_bf16(af[rt], bfr[ct], acc[rt][ct], 0, 0, 0);
    }

    __syncthreads();
    if (tid < BN) {
        float s = colpart_s[tid][0] + colpart_s[tid][1] + colpart_s[tid][2] + colpart_s[tid][3];
        float eps = (src == 0) ? 1e-5f : 1e-12f;
        colinv_s[tid] = 1.0f / fmaxf(sqrtf(s), eps);
    }
    __syncthreads();

    // ---- epilogue: cos = acc * colinv; label col -> posvals; others -> sum exp(64*cos)
#pragma unroll
    for (int rt = 0; rt < 4; ++rt) {
#pragma unroll
        for (int r = 0; r < 4; ++r) {
            int row = w * 64 + rt * 16 + q * 4 + r;
            int lab = label_s[row];
            float sum = 0.f;
#pragma unroll
            for (int ct = 0; ct < 4; ++ct) {
                int c = c0 + ct * 16 + ln;
                if (c < C) {
                    float cosv = acc[rt][ct][r] * colinv_s[ct * 16 + ln];
                    if (c == lab) posvals[src * B + row] = cosv;  // unique writer per (src,row)
                    else sum += __expf(S_SCALE * cosv);
                }
            }
            sum += __shfl_xor(sum, 1, 64);
            sum += __shfl_xor(sum, 2, 64);
            sum += __shfl_xor(sum, 4, 64);
            sum += __shfl_xor(sum, 8, 64);
            if (ln == 0) atomicAdd(&negacc[src * B + row], sum);
        }
    }
}

// ---------- final EPL loss ----------
__global__ void loss_kernel(const float* __restrict__ negacc, const float* __restrict__ posvals,
                            float* __restrict__ out) {
    int t = threadIdx.x;  // 256
    float l1 = log1pf(negacc[t] * __expf(-S_SCALE * (posvals[t] - M_MARGIN)));
    float l2 = log1pf(negacc[B + t] * __expf(-S_SCALE * (1.0f - K_VP) * posvals[B + t]));
    float p = l1 + l2;
    __shared__ float red[4];
    for (int off = 32; off > 0; off >>= 1) p += __shfl_down(p, off, 64);
    if ((t & 63) == 0) red[t >> 6] = p;
    __syncthreads();
    if (t == 0) out[0] = (red[0] + red[1] + red[2] + red[3]) / (2.0f * B);
}

extern "C" void kernel_launch(void* const* d_in, const int* in_sizes, int n_in,
                              void* d_out, int out_size, void* d_ws, size_t ws_size,
                              hipStream_t stream) {
    const float* input  = (const float*)d_in[0];
    const float* weight = (const float*)d_in[1];
    const float* queue  = (const float*)d_in[2];
    const int*   label  = (const int*)d_in[3];
    float* out = (float*)d_out;

    char* ws = (char*)d_ws;
    __bf16* embb_sw = (__bf16*)(ws);                         // 256 KB
    float*  newrows = (float*)(ws + (256 << 10));            // 512 KB
    float*  negacc  = (float*)(ws + (768 << 10));            // 2 KB
    float*  posvals = (float*)(ws + (768 << 10) + 2048);     // 2 KB
    int*    map     = (int*)  (ws + (768 << 10) + 4096);     // 400 KB

    init_kernel<<<(C + 255) / 256, 256, 0, stream>>>(map, negacc);
    scatter_kernel<<<1, B, 0, stream>>>(label, map);
    embnew_kernel<<<B, 256, 0, stream>>>(input, queue, label, embb_sw, newrows);
    gemm_epl_kernel<<<2 * NTILES, 256, 0, stream>>>(embb_sw, weight, queue, newrows, map,
                                                    label, negacc, posvals);
    loss_kernel<<<1, 256, 0, stream>>>(negacc, posvals, out);
}